// Round 8
// baseline (218.590 us; speedup 1.0000x reference)
//
#include <hip/hip_runtime.h>
#include <hip/hip_cooperative_groups.h>

namespace cg = cooperative_groups;

// Problem constants (static per reference)
constexpr int B_DIM   = 32;
constexpr int M_EDGES = 4096;     // edges per batch (2^12)
constexpr int F_DIM   = 64;
constexpr int N_ATOMS = 128;

constexpr int TOTAL_EDGES = B_DIM * M_EDGES;               // 131072
constexpr int CELLS       = B_DIM * N_ATOMS * N_ATOMS;     // 524288
constexpr int K_CAP       = 4;                             // dense 16B row per cell
constexpr unsigned int POOL_CAP = 4096;                    // overflow pool entries

constexpr int GRID_BLOCKS = 1024;                          // 4 blocks/CU x 256 CU
constexpr int BLOCK       = 256;
constexpr int NTHREADS    = GRID_BLOCKS * BLOCK;           // 262144

using f32x4 = __attribute__((ext_vector_type(4))) float;
using u32x4 = __attribute__((ext_vector_type(4))) unsigned int;

// One cooperative kernel: zero-metadata -> sync -> bin -> sync -> gather.
// Removes 2 inter-dispatch machine drains + the memset dispatch.
// __launch_bounds__(256,4): 4 waves/EU -> VGPR<=128 -> 4 blocks/CU ->
// 1024 blocks co-resident (cooperative-launch requirement).
__global__ __launch_bounds__(BLOCK, 4) void fused_scatter_kernel(
    const float*        __restrict__ edge,      // [B, M, F]
    const int*          __restrict__ pair,      // [B, M, 2] int32
    int*                __restrict__ counts,    // [CELLS]
    unsigned int*       __restrict__ list,      // [CELLS * 4]
    unsigned int*       __restrict__ pool_cnt,  // [1]
    unsigned long long* __restrict__ pool,      // [POOL_CAP]
    float*              __restrict__ out)       // [B, N, N, F]
{
    cg::grid_group grid = cg::this_grid();
    const int gtid = (int)(blockIdx.x * BLOCK + threadIdx.x);

    // ---- Phase A: zero counts (2 ints/thread, exactly CELLS) + pool ctr ----
    ((int2*)counts)[gtid] = make_int2(0, 0);
    if (gtid == 0) *pool_cnt = 0u;

    grid.sync();

    // ---- Phase B: bin edges (first TOTAL_EDGES threads, coalesced) --------
    if (gtid < TOTAL_EDGES) {
        const int e = gtid;
        const int2 ij = ((const int2*)pair)[e];
        const int b = e >> 12;
        const int cell = (b << 14) | (ij.x << 7) | ij.y;

        const int pos = atomicAdd(&counts[cell], 1);
        if (pos < K_CAP) {
            list[cell * K_CAP + pos] = (unsigned int)e;
        } else {
            const unsigned int pi = atomicAdd(pool_cnt, 1u);
            if (pi < POOL_CAP)
                pool[pi] = ((unsigned long long)(unsigned int)cell << 32)
                           | (unsigned int)e;
        }
    }

    grid.sync();

    // ---- Phase C: gather + single write per output quad -------------------
    // 16 threads/cell, one float4 of F each; 32 grid-strided units/thread so
    // consecutive threads write consecutive 16B -> contiguous wave stores.
    const f32x4* ef = (const f32x4*)edge;

    for (int u = 0; u < (CELLS * 16) / NTHREADS; ++u) {
        const int unit = u * NTHREADS + gtid;
        const int cell = unit >> 4;
        const int q    = unit & 15;

        const int cnt = counts[cell];
        f32x4 acc = (f32x4)0.0f;

        if (cnt > 0) {
            const u32x4 r = *reinterpret_cast<const u32x4*>(list + (size_t)cell * K_CAP);
            const unsigned int e0 = r.x;                  // valid: cnt >= 1
            const unsigned int e1 = cnt > 1 ? r.y : e0;   // clamp: stale never used
            const unsigned int e2 = cnt > 2 ? r.z : e0;
            const unsigned int e3 = cnt > 3 ? r.w : e0;

            const f32x4 a0 = ef[(size_t)e0 * 16 + q];     // 4 independent loads
            const f32x4 a1 = ef[(size_t)e1 * 16 + q];
            const f32x4 a2 = ef[(size_t)e2 * 16 + q];
            const f32x4 a3 = ef[(size_t)e3 * 16 + q];

            acc = a0;
            acc += a1 * (cnt > 1 ? 1.0f : 0.0f);
            acc += a2 * (cnt > 2 ? 1.0f : 0.0f);
            acc += a3 * (cnt > 3 ? 1.0f : 0.0f);

            if (cnt > K_CAP) {            // ~67 cells total; pool is L2-hot
                unsigned int pc = *pool_cnt;
                pc = pc > POOL_CAP ? POOL_CAP : pc;
                for (unsigned int t = 0; t < pc; ++t) {
                    const unsigned long long ent = pool[t];
                    if ((int)(ent >> 32) == cell)
                        acc += ef[(size_t)(unsigned int)ent * 16 + q];
                }
            }
        }

        ((f32x4*)out)[(size_t)cell * 16 + q] = acc;  // write IS the zero-fill
    }
}

extern "C" void kernel_launch(void* const* d_in, const int* in_sizes, int n_in,
                              void* d_out, int out_size, void* d_ws, size_t ws_size,
                              hipStream_t stream) {
    const float* edge = (const float*)d_in[0];
    const int*   pair = (const int*)d_in[1];
    float*       out  = (float*)d_out;

    // Workspace layout:
    //   [0, 2 MiB)                 counts (int32 x CELLS)
    //   [2 MiB, 2 MiB + 4)         pool counter
    //   [2 MiB + 16, + 32 KiB)     overflow pool (u64 x POOL_CAP)
    //   [2 MiB + 64 KiB, + 8 MiB)  dense list (uint4 per cell)
    char* ws = (char*)d_ws;
    int*                counts   = (int*)ws;
    unsigned int*       pool_cnt = (unsigned int*)(ws + (size_t)CELLS * 4);
    unsigned long long* pool     = (unsigned long long*)(ws + (size_t)CELLS * 4 + 16);
    unsigned int*       list     = (unsigned int*)(ws + (size_t)CELLS * 4 + 65536);

    void* args[] = { (void*)&edge, (void*)&pair, (void*)&counts, (void*)&list,
                     (void*)&pool_cnt, (void*)&pool, (void*)&out };

    hipLaunchCooperativeKernel((const void*)fused_scatter_kernel,
                               dim3(GRID_BLOCKS), dim3(BLOCK),
                               args, 0, stream);
}

// Round 9
// 57.508 us; speedup vs baseline: 3.8010x; 3.8010x over previous
//
#include <hip/hip_runtime.h>

// Problem constants (static per reference)
constexpr int B_DIM   = 32;
constexpr int M_EDGES = 4096;     // edges per batch (2^12)
constexpr int F_DIM   = 64;
constexpr int N_ATOMS = 128;

constexpr int TOTAL_EDGES = B_DIM * M_EDGES;               // 131072
constexpr int CELLS       = B_DIM * N_ATOMS * N_ATOMS;     // 524288
constexpr int K_CAP       = 4;                             // dense 16B row per cell
constexpr unsigned int POOL_CAP = 4096;                    // overflow pool entries

using f32x4 = __attribute__((ext_vector_type(4))) float;
using u32x4 = __attribute__((ext_vector_type(4))) unsigned int;

// ---------------------------------------------------------------------------
// Kernel A (node 2): zero-fill the whole 134 MB output (pure write stream at
// fill rate) AND bin the 131072 edges — one edge per thread for the first
// 512 of 1024 blocks. The bin's pair-load + atomic latency hides completely
// under the 32 independent fill stores per thread (BW-bound phase).
// ---------------------------------------------------------------------------
__global__ __launch_bounds__(256) void fill_and_bin_kernel(
    const int*          __restrict__ pair,      // [B, M, 2] int32
    int*                __restrict__ counts,    // [CELLS], pre-zeroed
    unsigned int*       __restrict__ list,      // [CELLS * 4]
    unsigned int*       __restrict__ pool_cnt,  // [1], pre-zeroed
    unsigned long long* __restrict__ pool,      // [POOL_CAP]
    float*              __restrict__ out)       // [B, N, N, F]
{
    const int tid = (int)threadIdx.x;
    const int blk = (int)blockIdx.x;            // 1024 blocks
    const int gid = blk * 256 + tid;

    // --- bin one edge (first TOTAL_EDGES threads); issued early so the
    // atomic's ~700-cycle latency overlaps the fill stores below.
    int  pos  = -1, cell = 0;
    if (gid < TOTAL_EDGES) {
        const int2 ij = ((const int2*)pair)[gid];
        const int b = gid >> 12;
        cell = (b << 14) | (ij.x << 7) | ij.y;
        pos  = atomicAdd(&counts[cell], 1);
    }

    // --- fill 512 B per thread: 32 f32x4 stores, block covers 128 KB.
    f32x4* o4 = (f32x4*)out + (size_t)blk * 8192;
    const f32x4 z = (f32x4)0.0f;
    #pragma unroll
    for (int k = 0; k < 32; ++k)
        o4[k * 256 + tid] = z;                  // 4 KB contiguous per instr

    // --- finish the bin (consume atomic result last).
    if (pos >= 0) {
        if (pos < K_CAP) {
            list[cell * K_CAP + pos] = (unsigned int)gid;
        } else {                                // ~70 edges in whole problem
            const unsigned int pi = atomicAdd(pool_cnt, 1u);
            if (pi < POOL_CAP)
                pool[pi] = ((unsigned long long)(unsigned int)cell << 32)
                           | (unsigned int)gid;
        }
    }
}

// ---------------------------------------------------------------------------
// Kernel B (node 3): sparse gather. 16 threads per cell, one float4 each.
// cnt==0 (78% of cells): exit after one coalesced 32B/wave metadata read —
// the zeros are already in place. Nonzero cells: dense 16B list row, clamped
// 4-wide independent edge loads, plain (non-atomic) overwrite store.
// ---------------------------------------------------------------------------
__global__ __launch_bounds__(256) void sparse_gather_kernel(
    const float*              __restrict__ edge,      // [B, M, F]
    const int*                __restrict__ counts,    // [CELLS]
    const unsigned int*       __restrict__ list,      // [CELLS * 4]
    const unsigned int*       __restrict__ pool_cnt,  // [1]
    const unsigned long long* __restrict__ pool,      // [POOL_CAP]
    float*                    __restrict__ out)       // [B, N, N, F]
{
    const int tid  = blockIdx.x * 256 + threadIdx.x;
    const int cell = tid >> 4;          // 16 threads per cell
    const int q    = tid & 15;          // which float4 of the 64 features

    const int cnt = counts[cell];       // broadcast across the 16 lanes
    if (cnt <= 0) return;               // zeros already written by kernel A

    const f32x4* ef = (const f32x4*)edge;

    const u32x4 r = *reinterpret_cast<const u32x4*>(list + (size_t)cell * K_CAP);
    const unsigned int e0 = r.x;                  // valid: cnt >= 1
    const unsigned int e1 = cnt > 1 ? r.y : e0;   // clamp: stale slots never used
    const unsigned int e2 = cnt > 2 ? r.z : e0;
    const unsigned int e3 = cnt > 3 ? r.w : e0;

    const f32x4 a0 = ef[(size_t)e0 * 16 + q];     // 4 independent loads
    const f32x4 a1 = ef[(size_t)e1 * 16 + q];
    const f32x4 a2 = ef[(size_t)e2 * 16 + q];
    const f32x4 a3 = ef[(size_t)e3 * 16 + q];

    f32x4 acc = a0;
    acc += a1 * (cnt > 1 ? 1.0f : 0.0f);
    acc += a2 * (cnt > 2 ? 1.0f : 0.0f);
    acc += a3 * (cnt > 3 ? 1.0f : 0.0f);

    if (cnt > K_CAP) {                  // ~67 cells total; pool is L2-hot
        unsigned int pc = *pool_cnt;
        pc = pc > POOL_CAP ? POOL_CAP : pc;
        for (unsigned int t = 0; t < pc; ++t) {
            const unsigned long long ent = pool[t];
            if ((int)(ent >> 32) == cell)
                acc += ef[(size_t)(unsigned int)ent * 16 + q];
        }
    }

    ((f32x4*)out)[(size_t)cell * 16 + q] = acc;   // plain overwrite of zeros
}

extern "C" void kernel_launch(void* const* d_in, const int* in_sizes, int n_in,
                              void* d_out, int out_size, void* d_ws, size_t ws_size,
                              hipStream_t stream) {
    const float* edge = (const float*)d_in[0];
    const int*   pair = (const int*)d_in[1];
    float*       out  = (float*)d_out;

    // Workspace layout:
    //   [0, 2 MiB)                 counts (int32 x CELLS)
    //   [2 MiB, 2 MiB + 4)         pool counter
    //   [2 MiB + 16, + 32 KiB)     overflow pool (u64 x POOL_CAP)
    //   [2 MiB + 64 KiB, + 8 MiB)  dense list (uint4 per cell)
    char* ws = (char*)d_ws;
    int*                counts   = (int*)ws;
    unsigned int*       pool_cnt = (unsigned int*)(ws + (size_t)CELLS * 4);
    unsigned long long* pool     = (unsigned long long*)(ws + (size_t)CELLS * 4 + 16);
    unsigned int*       list     = (unsigned int*)(ws + (size_t)CELLS * 4 + 65536);

    // Node 1: zero counts + pool counter (list/pool gated by counts).
    hipMemsetAsync(ws, 0, (size_t)CELLS * 4 + 16, stream);

    // Node 2: zero-fill output (pure write stream) + bin edges (piggyback).
    fill_and_bin_kernel<<<1024, 256, 0, stream>>>(pair, counts, list,
                                                  pool_cnt, pool, out);

    // Node 3: sparse gather — only nonzero cells load edges and store.
    sparse_gather_kernel<<<(CELLS * 16) / 256, 256, 0, stream>>>(
        edge, counts, list, pool_cnt, pool, out);
}

// Round 10
// 47.238 us; speedup vs baseline: 4.6274x; 1.2174x over previous
//
#include <hip/hip_runtime.h>

// Problem constants (static per reference)
constexpr int B_DIM   = 32;
constexpr int M_EDGES = 4096;     // edges per batch (2^12)
constexpr int F_DIM   = 64;
constexpr int N_ATOMS = 128;

constexpr int TOTAL_EDGES = B_DIM * M_EDGES;               // 131072
constexpr int CELLS       = B_DIM * N_ATOMS * N_ATOMS;     // 524288
constexpr int K_CAP       = 4;                             // dense 16B row per cell
constexpr unsigned int POOL_CAP = 4096;                    // overflow pool entries

constexpr int UPT            = 4;                          // units per gather thread
constexpr int GATHER_UNITS   = CELLS * 16;                 // 8,388,608 (cell x float4)
constexpr int GATHER_THREADS = GATHER_UNITS / UPT;         // 2,097,152

using f32x4 = __attribute__((ext_vector_type(4))) float;
using u32x4 = __attribute__((ext_vector_type(4))) unsigned int;

// ---------------------------------------------------------------------------
// Kernel 1: bin edges by destination cell. One atomicAdd + one 4B store per
// edge; ~70 edges (Poisson(0.25) tail) spill to a tiny pool.
// ---------------------------------------------------------------------------
__global__ __launch_bounds__(256) void bin_edges_kernel(
    const int*          __restrict__ pair,      // [B, M, 2] int32
    int*                __restrict__ counts,    // [CELLS]
    unsigned int*       __restrict__ list,      // [CELLS * 4]
    unsigned int*       __restrict__ pool_cnt,  // [1]
    unsigned long long* __restrict__ pool)      // [POOL_CAP]
{
    const int e = blockIdx.x * 256 + threadIdx.x;   // grid == TOTAL_EDGES
    const int2 ij = ((const int2*)pair)[e];
    const int b = e >> 12;

    const int cell = (b << 14) | (ij.x << 7) | ij.y;
    const int pos = atomicAdd(&counts[cell], 1);
    if (pos < K_CAP) {
        list[cell * K_CAP + pos] = (unsigned int)e;
    } else {
        const unsigned int pi = atomicAdd(pool_cnt, 1u);
        if (pi < POOL_CAP)
            pool[pi] = ((unsigned long long)(unsigned int)cell << 32) | (unsigned int)e;
    }
}

// ---------------------------------------------------------------------------
// Kernel 2: gather, 4 units/thread, fully hoisted and branchless.
//   - counts and list rows load IN PARALLEL (list no longer gated on cnt),
//     removing one dependent latency level;
//   - all 4 units' metadata, then all 16 edge loads, issue before any use:
//     one ~2-level latency chain instead of 4 serial 3-level chains;
//   - per-iteration stores stay wave-contiguous (1 KB) via NTHREADS stride.
// Stale list slots are clamped (cnt==0 -> edge 0) so loads are in-bounds and
// blended away with 0/1 factors. Output written exactly once = zero-fill.
// ---------------------------------------------------------------------------
__global__ __launch_bounds__(256, 4) void gather_write_kernel(
    const float*              __restrict__ edge,      // [B, M, F]
    const int*                __restrict__ counts,    // [CELLS]
    const unsigned int*       __restrict__ list,      // [CELLS * 4]
    const unsigned int*       __restrict__ pool_cnt,  // [1]
    const unsigned long long* __restrict__ pool,      // [POOL_CAP]
    float*                    __restrict__ out)       // [B, N, N, F]
{
    const int gtid = blockIdx.x * 256 + threadIdx.x;
    const f32x4* ef = (const f32x4*)edge;

    int   cnt[UPT];
    u32x4 r[UPT];

    // --- metadata for all 4 units: 8 independent loads, issue together ----
    #pragma unroll
    for (int k = 0; k < UPT; ++k) {
        const int unit = gtid + k * GATHER_THREADS;
        const int cell = unit >> 4;
        cnt[k] = counts[cell];
        r[k]   = *reinterpret_cast<const u32x4*>(list + (size_t)cell * K_CAP);
    }

    // --- edge ids (clamped: stale slots never dereferenced meaningfully) --
    unsigned int e0[UPT], e1[UPT], e2[UPT], e3[UPT];
    #pragma unroll
    for (int k = 0; k < UPT; ++k) {
        e0[k] = cnt[k] > 0 ? r[k].x : 0u;      // cnt==0 -> edge 0 (in-bounds)
        e1[k] = cnt[k] > 1 ? r[k].y : e0[k];
        e2[k] = cnt[k] > 2 ? r[k].z : e0[k];
        e3[k] = cnt[k] > 3 ? r[k].w : e0[k];
    }

    // --- all 16 edge loads, issue together --------------------------------
    f32x4 a0[UPT], a1[UPT], a2[UPT], a3[UPT];
    #pragma unroll
    for (int k = 0; k < UPT; ++k) {
        const int q = (gtid + k * GATHER_THREADS) & 15;
        a0[k] = ef[(size_t)e0[k] * 16 + q];
        a1[k] = ef[(size_t)e1[k] * 16 + q];
        a2[k] = ef[(size_t)e2[k] * 16 + q];
        a3[k] = ef[(size_t)e3[k] * 16 + q];
    }

    // --- blend + (rare) pool + store --------------------------------------
    #pragma unroll
    for (int k = 0; k < UPT; ++k) {
        const int unit = gtid + k * GATHER_THREADS;

        f32x4 acc = a0[k] * (cnt[k] > 0 ? 1.0f : 0.0f);
        acc += a1[k] * (cnt[k] > 1 ? 1.0f : 0.0f);
        acc += a2[k] * (cnt[k] > 2 ? 1.0f : 0.0f);
        acc += a3[k] * (cnt[k] > 3 ? 1.0f : 0.0f);

        if (cnt[k] > K_CAP) {           // ~67 cells in the whole problem
            const int cell = unit >> 4;
            const int q    = unit & 15;
            unsigned int pc = *pool_cnt;
            pc = pc > POOL_CAP ? POOL_CAP : pc;
            for (unsigned int t = 0; t < pc; ++t) {   // pool is L2-hot
                const unsigned long long ent = pool[t];
                if ((int)(ent >> 32) == cell)
                    acc += ef[(size_t)(unsigned int)ent * 16 + q];
            }
        }

        ((f32x4*)out)[unit] = acc;      // wave-contiguous 1KB per iteration
    }
}

extern "C" void kernel_launch(void* const* d_in, const int* in_sizes, int n_in,
                              void* d_out, int out_size, void* d_ws, size_t ws_size,
                              hipStream_t stream) {
    const float* edge = (const float*)d_in[0];
    const int*   pair = (const int*)d_in[1];
    float*       out  = (float*)d_out;

    // Workspace layout:
    //   [0, 2 MiB)                 counts (int32 x CELLS)
    //   [2 MiB, 2 MiB + 4)         pool counter
    //   [2 MiB + 16, + 32 KiB)     overflow pool (u64 x POOL_CAP)
    //   [2 MiB + 64 KiB, + 8 MiB)  dense list (uint4 per cell)
    char* ws = (char*)d_ws;
    int*                counts   = (int*)ws;
    unsigned int*       pool_cnt = (unsigned int*)(ws + (size_t)CELLS * 4);
    unsigned long long* pool     = (unsigned long long*)(ws + (size_t)CELLS * 4 + 16);
    unsigned int*       list     = (unsigned int*)(ws + (size_t)CELLS * 4 + 65536);

    // Node 1: zero counts + pool counter (list/pool gated by counts).
    hipMemsetAsync(ws, 0, (size_t)CELLS * 4 + 16, stream);

    // Node 2: bin edges (512 blocks).
    bin_edges_kernel<<<TOTAL_EDGES / 256, 256, 0, stream>>>(pair, counts, list,
                                                            pool_cnt, pool);

    // Node 3: gather, 4 units/thread (8192 blocks).
    gather_write_kernel<<<GATHER_THREADS / 256, 256, 0, stream>>>(
        edge, counts, list, pool_cnt, pool, out);
}